// Round 2
// baseline (2086.099 us; speedup 1.0000x reference)
//
#include <hip/hip_runtime.h>

// ---------------------------------------------------------------------------
// PerTokenFN: out[b,t,:] = GELU(x[b,t,:] @ W1[t] + b1[t]) @ W2[t] + b2[t]
// B=4096, T=64, D=256, H=1024.  fp32 in/out, bf16 MFMA compute.
//
// Round-1 bisect build: NO d_ws, NO prepass, NO global_load_lds, NO dbuf.
// Weights are converted fp32->bf16 on the fly into the same swizzled LDS
// images as round 0; fragment reads / MFMA / h round-trip / epilogue are
// unchanged. Exact erff GELU. Classic 2-barrier staging per K-step.
// ---------------------------------------------------------------------------

typedef __bf16 bf16x8 __attribute__((ext_vector_type(8)));
typedef float  floatx4 __attribute__((ext_vector_type(4)));

__device__ __forceinline__ unsigned short f2bf(float f) {
  unsigned u = __builtin_bit_cast(unsigned, f);
  u += 0x7fffu + ((u >> 16) & 1u);   // RNE
  return (unsigned short)(u >> 16);
}

__device__ __forceinline__ float gelu_exact(float v) {
  return 0.5f * v * (1.0f + erff(v * 0.70710678118654752f));
}

// ---------------------------------------------------------------------------
// LDS images (per K-step tiles):
//  W1 image (8 KB):  elem(jl in[0,128), dl=q*8+i in[0,32)) at
//                    jl*64 + ((q ^ ((jl>>1)&3))*16) + i*2
//  W2 image (16 KB): elem(d in[0,256),  jl32=q*8+i in[0,32)) at
//                    d*64 + ((q ^ ((d>>1)&3))*16) + i*2
//  h image (16 KB):  elem(b in[0,64), jl in[0,128)) at
//                    b*256 + (((jl>>3) ^ (b&7))*16) + (jl&7)*2
// ---------------------------------------------------------------------------
__global__ __launch_bounds__(256, 2) void mlp_kernel(
    const float* __restrict__ x, const float* __restrict__ w1,
    const float* __restrict__ b1, const float* __restrict__ w2,
    const float* __restrict__ b2, float* __restrict__ out) {

  __shared__ __attribute__((aligned(16))) unsigned char lds[40960];
  unsigned char* const w1img = lds;            // [0, 8192)
  unsigned char* const w2img = lds + 8192;     // [8192, 24576)
  unsigned char* const hlds  = lds + 24576;    // [24576, 40960)

  const int tid  = threadIdx.x;
  const int lane = tid & 63;
  const int w    = tid >> 6;        // 0..3
  const int wm   = w >> 1;          // GEMM1 b-half
  const int wn   = w & 1;           // GEMM1 j-half
  const int l15  = lane & 15;
  const int l4   = lane >> 4;       // 0..3

  // XCD-friendly: each t pinned to one XCD (bid & 7)
  const int bid  = blockIdx.x;
  const int t    = (bid & 7) + 8 * (bid >> 9);
  const int b0   = ((bid >> 3) & 63) << 6;

  const float* w1t = w1 + (size_t)t * 262144;   // [D=256][H=1024]
  const float* w2t = w2 + (size_t)t * 262144;   // [H=1024][D=256]

  // ---- staging thread assignments ----
  const int jl_s   = tid & 127;                 // W1: image row
  const int half_s = tid >> 7;                  // W1: dl half (16 each)
  const int P_s    = half_s ^ ((jl_s >> 2) & 1);
  const int sw2s   = (tid >> 1) & 3;            // W2: d = tid swizzle

  // ---- x fragments: A-operand of GEMM1, held in registers ----
  bf16x8 xfrag[2][8];
#pragma unroll
  for (int mt = 0; mt < 2; ++mt) {
    const int b = b0 + wm * 32 + mt * 16 + l15;
    const float* xb = x + ((size_t)b * 64 + t) * 256 + l4 * 8;
#pragma unroll
    for (int kk = 0; kk < 8; ++kk) {
      floatx4 lo = *(const floatx4*)(xb + kk * 32);
      floatx4 hi = *(const floatx4*)(xb + kk * 32 + 4);
      union { bf16x8 v; unsigned short s[8]; } px;
      px.s[0] = f2bf(lo[0]); px.s[1] = f2bf(lo[1]);
      px.s[2] = f2bf(lo[2]); px.s[3] = f2bf(lo[3]);
      px.s[4] = f2bf(hi[0]); px.s[5] = f2bf(hi[1]);
      px.s[6] = f2bf(hi[2]); px.s[7] = f2bf(hi[3]);
      xfrag[mt][kk] = px.v;
    }
  }

  // ---- out^T accumulators (GEMM2: M=d rows, N=b cols), init with b2 ----
  floatx4 oacc[4][4];
#pragma unroll
  for (int mt = 0; mt < 4; ++mt) {
    const floatx4 bv = *(const floatx4*)(b2 + t * 256 + w * 64 + mt * 16 + l4 * 4);
#pragma unroll
    for (int nt = 0; nt < 4; ++nt) oacc[mt][nt] = bv;
  }

  // lane-constant fragment offsets (swizzle depends only on lane bits 1..2)
  const int swf    = (l4 ^ ((lane >> 1) & 3)) << 4;
  const int w1base = ((wn * 64 + l15) << 6) + swf;  // + nt*1024
  const int w2base = ((w * 64 + l15) << 6) + swf;   // + mt*1024

#pragma unroll 1
  for (int c = 0; c < 8; ++c) {
    // h accumulators (GEMM1 wave tile: 32 b-rows x 64 j-cols), init b1
    floatx4 hacc[2][4];
#pragma unroll
    for (int nt = 0; nt < 4; ++nt) {
      const float bv = b1[t * 1024 + c * 128 + wn * 64 + nt * 16 + l15];
      const floatx4 bb = {bv, bv, bv, bv};
      hacc[0][nt] = bb; hacc[1][nt] = bb;
    }

    // ---------------- GEMM1: K = D = 256, 8 steps of 32 ----------------
#pragma unroll
    for (int kk = 0; kk < 8; ++kk) {
      // load fp32 W1 sub-tile: thread covers (jl_s, dl = half_s*16 + u)
      float f[16];
      const float* src = w1t + (size_t)(kk * 32 + half_s * 16) * 1024 + c * 128 + jl_s;
#pragma unroll
      for (int u = 0; u < 16; ++u) f[u] = src[(size_t)u * 1024];

      __syncthreads();   // previous image readers done
      union { uint4 v; unsigned short s[8]; } pk[2];
#pragma unroll
      for (int u = 0; u < 16; ++u) pk[u >> 3].s[u & 7] = f2bf(f[u]);
#pragma unroll
      for (int p = 0; p < 2; ++p) {
        const int m = 2 * P_s + p;                 // physical 16B slot
        const int s = (p ^ (jl_s >> 1)) & 1;       // chunk q = m ^ sw -> q&1
        *(uint4*)(w1img + jl_s * 64 + m * 16) = pk[s].v;
      }
      __syncthreads();   // image visible

      bf16x8 bfrag[4];
#pragma unroll
      for (int nt = 0; nt < 4; ++nt)
        bfrag[nt] = *(const bf16x8*)(w1img + w1base + nt * 1024);
#pragma unroll
      for (int mt = 0; mt < 2; ++mt)
#pragma unroll
        for (int nt = 0; nt < 4; ++nt)
          hacc[mt][nt] = __builtin_amdgcn_mfma_f32_16x16x32_bf16(
              xfrag[mt][kk], bfrag[nt], hacc[mt][nt], 0, 0, 0);
    }

    // ---------------- GELU + h -> LDS (swizzled [b][j] image) ----------
#pragma unroll
    for (int mt = 0; mt < 2; ++mt) {
#pragma unroll
      for (int nt = 0; nt < 4; ++nt) {
        const int jl = wn * 64 + nt * 16 + l15;
        const int q  = jl >> 3;
        const int jo = (jl & 7) * 2;
#pragma unroll
        for (int r = 0; r < 4; ++r) {
          const float g = gelu_exact(hacc[mt][nt][r]);
          const int b = wm * 32 + mt * 16 + l4 * 4 + r;
          *(unsigned short*)(hlds + b * 256 + ((q ^ (b & 7)) * 16) + jo) = f2bf(g);
        }
      }
    }

    // ---------------- GEMM2: K = 128 (chunk j), 4 steps of 32 ----------
#pragma unroll
    for (int kk2 = 0; kk2 < 4; ++kk2) {
      // load fp32 W2 sub-tile: thread covers (d = tid, jl32 = 0..31)
      float g2[32];
      const float* src2 = w2t + (size_t)(c * 128 + kk2 * 32) * 256 + tid;
#pragma unroll
      for (int v = 0; v < 32; ++v) g2[v] = src2[(size_t)v * 256];

      __syncthreads();   // previous readers (incl. h-store drain at kk2=0)
      union { uint4 v; unsigned short s[8]; } pk2[4];
#pragma unroll
      for (int v = 0; v < 32; ++v) pk2[v >> 3].s[v & 7] = f2bf(g2[v]);
#pragma unroll
      for (int p = 0; p < 4; ++p) {
        const int m = (p + (tid >> 1)) & 3;        // conflict-free slot order
        const int q = m ^ sw2s;                    // chunk stored at slot m
        *(uint4*)(w2img + tid * 64 + m * 16) = pk2[q].v;
      }
      __syncthreads();   // image visible

      bf16x8 afrag[4];
#pragma unroll
      for (int mt = 0; mt < 4; ++mt)
        afrag[mt] = *(const bf16x8*)(w2img + w2base + mt * 1024);
      bf16x8 hfrag[4];
#pragma unroll
      for (int nt = 0; nt < 4; ++nt)
        hfrag[nt] = *(const bf16x8*)(hlds + (nt * 16 + l15) * 256 +
                                     (((kk2 * 4 + l4) ^ (lane & 7)) * 16));
#pragma unroll
      for (int mt = 0; mt < 4; ++mt)
#pragma unroll
        for (int nt = 0; nt < 4; ++nt)
          oacc[mt][nt] = __builtin_amdgcn_mfma_f32_16x16x32_bf16(
              afrag[mt], hfrag[nt], oacc[mt][nt], 0, 0, 0);
    }
  }

  // ---- epilogue: out^T regs -> out[b][t][d], 4 consecutive d per lane ----
#pragma unroll
  for (int mt = 0; mt < 4; ++mt) {
    const int d = w * 64 + mt * 16 + l4 * 4;
#pragma unroll
    for (int nt = 0; nt < 4; ++nt) {
      const int b = b0 + nt * 16 + l15;
      *(floatx4*)(out + ((size_t)b * 64 + t) * 256 + d) = oacc[mt][nt];
    }
  }
}

// ---------------------------------------------------------------------------
extern "C" void kernel_launch(void* const* d_in, const int* in_sizes, int n_in,
                              void* d_out, int out_size, void* d_ws, size_t ws_size,
                              hipStream_t stream) {
  const float* x  = (const float*)d_in[0];
  const float* W1 = (const float*)d_in[1];
  const float* b1 = (const float*)d_in[2];
  const float* W2 = (const float*)d_in[3];
  const float* b2 = (const float*)d_in[4];
  float* out = (float*)d_out;

  mlp_kernel<<<4096, 256, 0, stream>>>(x, W1, b1, W2, b2, out);
}